// Round 5
// baseline (922.981 us; speedup 1.0000x reference)
//
#include <hip/hip_runtime.h>

typedef unsigned short u16;
typedef unsigned int   u32;
typedef unsigned long long u64;
typedef __bf16 bf16x8 __attribute__((ext_vector_type(8)));
typedef float  floatx4 __attribute__((ext_vector_type(4)));

#define DEV static __device__ __forceinline__

DEV u16 f2bf(float f){ u32 x = __float_as_uint(f); return (u16)((x + 0x7fffu + ((x>>16)&1u)) >> 16); }
DEV float bf2f(u16 h){ return __uint_as_float(((u32)h)<<16); }

DEV void load_lds16(const u16* g, u16* l){
  __builtin_amdgcn_global_load_lds((const __attribute__((address_space(1))) u32*)g,
                                   (__attribute__((address_space(3))) u32*)l, 16, 0, 0);
}

// ---------------------------------------------------------------------------
// Generic NT GEMM: C[m,n] = sum_k A[m,k]*B[n,k]  (A,B bf16 row-major, C fp32)
// BM in {64,128}, BN in {64,128}, BK=32, 256 threads (4 waves as 2x2).
// MODE 0: C fp32 (+optional bias[n]), stores guarded by col<ncmax.
// MODE 1 (BN=64): AV epilogue — res[z][i][d] (+)= alpha*C (alpha=sigmoid),
//   and vout[z][d][i] = bf16(C) (transposed) for the next order.
// ---------------------------------------------------------------------------
template<int BM, int BN, int MODE>
__global__ __launch_bounds__(256) void gemm_bt(
    const u16* __restrict__ A, const u16* __restrict__ Bm, float* __restrict__ C,
    const float* __restrict__ bias, int K, int lda, int ldb, int ldc, int ncmax,
    long long sA, long long sB, long long sC,
    u16* __restrict__ vout, float* __restrict__ resb, const float* __restrict__ araw,
    int order, int accum)
{
  constexpr int BK = 32;
  constexpr int MT = BM/32;               // m-tiles per wave (wave covers BM/2 rows)
  constexpr int NT = (BN/2)/16;           // n-tiles per wave
  __shared__ u16 smem[8704];              // staging (<=8192 u16) / 64x136 transpose
  u16* As = smem;                         // BM*BK u16
  u16* Bs = smem + BM*BK;                 // BN*BK u16

  const int tid = threadIdx.x, wid = tid>>6, lane = tid&63;
  const int z = blockIdx.z;
  const int m0 = blockIdx.y * BM, n0 = blockIdx.x * BN;
  const u16* Ab = A + (long long)z*sA;
  const u16* Bb = Bm + (long long)z*sB;

  const int srow = tid>>2, schunk = (tid&3)*8;
  const u16* ga0 = Ab + (long long)(m0 + srow)*lda + schunk;
  const u16* gb0 = Bb + (long long)(n0 + srow)*ldb + schunk;
  const u16* ga1 = (BM==128) ? Ab + (long long)(m0 + 64 + srow)*lda + schunk : nullptr;
  const u16* gb1 = (BN==128) ? Bb + (long long)(n0 + 64 + srow)*ldb + schunk : nullptr;

  u16* lA0 = As + (wid*16)*BK;
  u16* lA1 = As + (64 + wid*16)*BK;
  u16* lB0 = Bs + (wid*16)*BK;
  u16* lB1 = Bs + (64 + wid*16)*BK;

  const int wm = wid>>1, wn = wid&1;
  const int lr = lane&15, lk = (lane>>4)*8, lq = lane>>4;

  floatx4 acc[MT][NT] = {};

  for (int k = 0; k < K; k += BK) {
    __syncthreads();
    load_lds16(ga0 + k, lA0);
    if constexpr (BM == 128) load_lds16(ga1 + k, lA1);
    load_lds16(gb0 + k, lB0);
    if constexpr (BN == 128) load_lds16(gb1 + k, lB1);
    __syncthreads();
    bf16x8 af[MT];
#pragma unroll
    for (int mt=0; mt<MT; ++mt)
      af[mt] = *(const bf16x8*)(As + (wm*(BM/2) + mt*16 + lr)*BK + lk);
#pragma unroll
    for (int nt=0; nt<NT; ++nt) {
      bf16x8 bfr = *(const bf16x8*)(Bs + (wn*(BN/2) + nt*16 + lr)*BK + lk);
#pragma unroll
      for (int mt=0; mt<MT; ++mt)
        acc[mt][nt] = __builtin_amdgcn_mfma_f32_16x16x32_bf16(af[mt], bfr, acc[mt][nt], 0, 0, 0);
    }
  }

  if constexpr (MODE == 0) {
    float* Cb = C + (long long)z*sC;
#pragma unroll
    for (int nt=0; nt<NT; ++nt) {
      const int col = n0 + wn*(BN/2) + nt*16 + lr;
      if (col < ncmax) {
        const float bv = bias ? bias[col] : 0.f;
#pragma unroll
        for (int mt=0; mt<MT; ++mt) {
#pragma unroll
          for (int r=0; r<4; ++r) {
            const int row = m0 + wm*(BM/2) + mt*16 + lq*4 + r;
            Cb[(long long)row*ldc + col] = acc[mt][nt][r] + bv;
          }
        }
      }
    }
  } else {
    const int h = z & 15;
    const float alpha = 1.f/(1.f + __expf(-araw[order*16 + h]));
    float* rb = resb + (long long)z * 65536;   // res[z][1024][64]
    __syncthreads();                           // staging LDS reuse as transpose buf
#pragma unroll
    for (int nt=0; nt<NT; ++nt) {
      const int d = wn*32 + nt*16 + lr;
#pragma unroll
      for (int mt=0; mt<MT; ++mt) {
#pragma unroll
        for (int r=0; r<4; ++r) {
          const int row = wm*(BM/2) + mt*16 + lq*4 + r;
          const float v = acc[mt][nt][r];
          const long long ri = (long long)(m0+row)*64 + d;
          rb[ri] = accum ? (rb[ri] + alpha*v) : (alpha*v);
          smem[d*136 + row] = f2bf(v);
        }
      }
    }
    __syncthreads();
    const int dd = tid>>2, cc = (tid&3)*(BM/4);
    u16* vp = vout + (long long)z*75776 + (long long)dd*1184 + m0 + cc;  // vout[z][64][1184]
    const u16* sp = smem + dd*136 + cc;
#pragma unroll
    for (int j=0; j<BM/4; j+=8) {
      uint4 uu;
      uu.x = sp[j+0] | ((u32)sp[j+1]<<16);
      uu.y = sp[j+2] | ((u32)sp[j+3]<<16);
      uu.z = sp[j+4] | ((u32)sp[j+5]<<16);
      uu.w = sp[j+6] | ((u32)sp[j+7]<<16);
      *(uint4*)(vp + j) = uu;
    }
  }
}

// ---------------------------------------------------------------------------
// Fused scores + top-k + softmax. One block = (one z, 16 Q-rows, all cols).
// Score phase: MFMA direct-from-global (no LDS staging); wave w computes
// n-tiles [w*19, w*19+19) -> cols w*304..w*304+303 (covers 0..1215 >= 1153).
// Scores land in LDS (stride 1164 words -> 2-way-free banks). Top-k phase:
// wave w owns rows w*4..w*4+3: band-add from own row's rel cols (1024..1152),
// exact early-exit radix select, softmax, write P bf16 (dense, 1184 cols).
// K-accumulation order identical to the old GEMM -> bit-identical scores.
// ---------------------------------------------------------------------------
__global__ __launch_bounds__(256) void score_topk(
    const u16* __restrict__ qS,   // [z][1024][192]
    const u16* __restrict__ kxS,  // [z][1280][192]
    u16* __restrict__ P)          // [z][1024][1184]
{
  constexpr int SROW = 1164;
  __shared__ float sm[16*SROW];   // 74,496 B
  const int tid = threadIdx.x, wid = tid>>6, lane = tid&63;
  const int z = blockIdx.x, m0 = blockIdx.y*16;
  const int lr = lane&15, lk = (lane>>4)*8, lq = lane>>4;

  const u16* Ab = qS  + ((long long)z*1024 + m0)*192;
  const u16* Bb = kxS + (long long)z*245760;
  const int wn0 = wid*304;

  floatx4 acc[19];
#pragma unroll
  for (int nt=0;nt<19;++nt) acc[nt] = floatx4{0.f,0.f,0.f,0.f};

  for (int k=0; k<192; k+=32){
    const bf16x8 af = *(const bf16x8*)(Ab + lr*192 + k + lk);
#pragma unroll
    for (int nt=0;nt<19;++nt){
      const bf16x8 bq = *(const bf16x8*)(Bb + (long long)(wn0 + nt*16 + lr)*192 + k + lk);
      acc[nt] = __builtin_amdgcn_mfma_f32_16x16x32_bf16(af, bq, acc[nt], 0, 0, 0);
    }
  }
#pragma unroll
  for (int nt=0;nt<19;++nt){
    const int col = wn0 + nt*16 + lr;
    if (col < 1153){
#pragma unroll
      for (int r=0;r<4;++r) sm[(lq*4+r)*SROW + col] = acc[nt][r];
    }
  }
  __syncthreads();

  for (int rr=0; rr<4; ++rr){
    const int row = wid*4 + rr;
    const int i = m0 + row;
    float* R = sm + row*SROW;

    float v[16];
#pragma unroll
    for (int x=0;x<16;++x) v[x] = R[x*64 + lane];
#pragma unroll
    for (int x=0;x<16;++x){
      const int j = x*64 + lane;
      int dl = i - j; dl = dl > 64 ? 64 : (dl < -64 ? -64 : dl);
      v[x] += R[1024 + dl + 64];
    }
    u32 u[16];
#pragma unroll
    for (int x=0;x<16;++x){
      u32 bb = __float_as_uint(v[x]);
      u[x] = bb ^ ((u32)((int)bb >> 31) | 0x80000000u);
    }
    u32 thr = 0;
#pragma unroll 1
    for (int bit=31; bit>=0; --bit){
      const u32 cand = thr | (1u<<bit);
      int c = 0;
#pragma unroll
      for (int x=0;x<16;++x) c += __popcll(__ballot(u[x] >= cand));
      if (c == 256){
        u32 mn = 0xFFFFFFFFu;
#pragma unroll
        for (int x=0;x<16;++x) if (u[x] >= cand && u[x] < mn) mn = u[x];
        for (int o=32;o;o>>=1){ u32 t = __shfl_xor(mn, o); mn = t < mn ? t : mn; }
        thr = mn;
        break;
      }
      if (c > 256) thr = cand;
    }
    float m = -3.0e38f;
#pragma unroll
    for (int x=0;x<16;++x) m = fmaxf(m, v[x]);
    for (int o=32;o;o>>=1) m = fmaxf(m, __shfl_xor(m, o));
    float e[16]; float Z = 0.f;
#pragma unroll
    for (int x=0;x<16;++x){
      e[x] = (u[x] >= thr) ? __expf(v[x]-m) : 0.f;
      Z += e[x];
    }
    for (int o=32;o;o>>=1) Z += __shfl_xor(Z, o);
    const float rz = 1.f / Z;

    u16* Pr = P + ((long long)z*1024 + i)*1184;
#pragma unroll
    for (int x=0;x<16;++x){
      const float p = e[x]*rz;
      R[x*64 + lane] = p;            // p over score cols (rel cols untouched)
      Pr[x*64 + lane] = f2bf(p);
    }
    float s0 = 0.f, s1 = 0.f;
#pragma unroll
    for (int x=0;x<16;++x){
      const int j = x*64 + lane;
      const float p = e[x]*rz;
      if (j >= i+64) s0 += p;        // dist bucket t=0
      if (j <= i-64) s1 += p;        // dist bucket t=128
    }
    for (int o=32;o;o>>=1){ s0 += __shfl_xor(s0,o); s1 += __shfl_xor(s1,o); }
    __syncthreads();                 // order p LDS writes before band reads (uniform: 4 iters/wave)
    {
      const int t = lane + 1;        // 1..64
      const int j = i + 64 - t;
      const float wv = (j>=0 && j<1024) ? R[j] : 0.f;
      Pr[1024 + t] = f2bf(wv);
      if (lane < 63){
        const int t2 = lane + 65;    // 65..127
        const int j2 = i + 64 - t2;
        const float wv2 = (j2>=0 && j2<1024) ? R[j2] : 0.f;
        Pr[1024 + t2] = f2bf(wv2);
      }
      if (lane == 0){ Pr[1024] = f2bf(s0); Pr[1152] = f2bf(s1); }
      if (lane >= 33) Pr[1120 + lane] = 0;  // zero cols 1153..1183
    }
  }
}

// ---------------------------------------------------------------------------
// Elementwise prep kernels
// ---------------------------------------------------------------------------
__global__ __launch_bounds__(256) void planeize(const float* __restrict__ src, u16* __restrict__ dst,
                                                int total, int modeB){
  int idx = blockIdx.x*256 + threadIdx.x;
  if (idx >= total) return;
  int c = idx & 1023, r = idx >> 10;
  float v = src[idx];
  u16 hi = f2bf(v); u16 lo = f2bf(v - bf2f(hi));
  u16* d = dst + (long long)r*3072 + c;
  if (modeB){ d[0]=hi; d[1024]=hi; d[2048]=lo; }
  else      { d[0]=hi; d[1024]=lo; d[2048]=hi; }
}

__global__ __launch_bounds__(256) void build_qk(const float* __restrict__ qkv,
                                                u16* __restrict__ qS, u16* __restrict__ kxS){
  int idx = blockIdx.x*256 + threadIdx.x;   // ((b*16+h)*1024+n)*64+d
  int d = idx & 63, n = (idx>>6) & 1023, bh = idx >> 16;
  int b = bh >> 4, h = bh & 15;
  long long src = (long long)(b*1024 + n)*3072 + h*64 + d;
  float qv = qkv[src];
  float kv = qkv[src + 1024] * 0.125f;
  u16 qhi=f2bf(qv), qlo=f2bf(qv - bf2f(qhi));
  u16 khi=f2bf(kv), klo=f2bf(kv - bf2f(khi));
  u16* q  = qS  + ((long long)bh*1024 + n)*192 + d;
  q[0]=qhi; q[64]=qlo; q[128]=qhi;
  u16* kx = kxS + ((long long)bh*1280 + n)*192 + d;
  kx[0]=khi; kx[64]=khi; kx[128]=klo;
}

__global__ __launch_bounds__(256) void build_kxrel(const float* __restrict__ relk, u16* __restrict__ kxS){
  int idx = blockIdx.x*256 + threadIdx.x;   // (bh, t:256, d:64)
  int d = idx & 63, t = (idx>>6) & 255, bh = idx >> 14;
  u16 hi=0, lo=0;
  if (t < 129){ float v = relk[t*64 + d]; hi = f2bf(v); lo = f2bf(v - bf2f(hi)); }
  u16* kx = kxS + ((long long)bh*1280 + 1024 + t)*192 + d;
  kx[0]=hi; kx[64]=hi; kx[128]=lo;
}

__global__ __launch_bounds__(256) void build_vT(const float* __restrict__ qkv, u16* __restrict__ vA){
  __shared__ float tb[64][65];
  int bh = blockIdx.x >> 4, ntile = blockIdx.x & 15;
  int b = bh >> 4, h = bh & 15;
  int tid = threadIdx.x;
  int nl = tid >> 2, dc = (tid & 3)*16;
  const float* sp = qkv + (long long)(b*1024 + ntile*64 + nl)*3072 + 2048 + h*64 + dc;
#pragma unroll
  for (int j=0;j<16;j+=4){
    float4 f = *(const float4*)(sp + j);
    tb[dc+j+0][nl]=f.x; tb[dc+j+1][nl]=f.y; tb[dc+j+2][nl]=f.z; tb[dc+j+3][nl]=f.w;
  }
  __syncthreads();
  int d = tid >> 2, nc = (tid & 3)*16;
  u16* dp = vA + ((long long)bh*64 + d)*1184 + ntile*64 + nc;
#pragma unroll
  for (int j=0;j<16;j+=8){
    u16 a0=f2bf(tb[d][nc+j+0]), a1=f2bf(tb[d][nc+j+1]), a2=f2bf(tb[d][nc+j+2]), a3=f2bf(tb[d][nc+j+3]);
    u16 a4=f2bf(tb[d][nc+j+4]), a5=f2bf(tb[d][nc+j+5]), a6=f2bf(tb[d][nc+j+6]), a7=f2bf(tb[d][nc+j+7]);
    uint4 uu; uu.x=a0|((u32)a1<<16); uu.y=a2|((u32)a3<<16); uu.z=a4|((u32)a5<<16); uu.w=a6|((u32)a7<<16);
    *(uint4*)(dp + j) = uu;
  }
}

__global__ __launch_bounds__(256) void build_vText(const float* __restrict__ relv, u16* __restrict__ vA){
  int idx = blockIdx.x*256 + threadIdx.x;   // (bh, d, t:160)
  int t = idx % 160; int rest = idx / 160; int d = rest & 63; int bh = rest >> 6;
  u16 hv = 0;
  if (t < 129) hv = f2bf(relv[t*64 + d]);
  vA[((long long)bh*64 + d)*1184 + 1024 + t] = hv;
}

__global__ __launch_bounds__(256) void build_resS(const float* __restrict__ res, u16* __restrict__ resS){
  int idx = blockIdx.x*256 + threadIdx.x;
  int d = idx & 63, n = (idx>>6) & 1023, bh = idx >> 16;
  int b = bh >> 4, h = bh & 15;
  float v = res[idx];
  u16 hi = f2bf(v), lo = f2bf(v - bf2f(hi));
  u16* p = resS + (long long)(b*1024 + n)*3072 + h*64 + d;
  p[0]=hi; p[1024]=lo; p[2048]=hi;
}

// ---------------------------------------------------------------------------
extern "C" void kernel_launch(void* const* d_in, const int* in_sizes, int n_in,
                              void* d_out, int out_size, void* d_ws, size_t ws_size,
                              hipStream_t stream) {
  const float* x    = (const float*)d_in[0];
  const float* Wqkv = (const float*)d_in[1];
  const float* bqkv = (const float*)d_in[2];
  const float* Wout = (const float*)d_in[3];
  const float* bout = (const float*)d_in[4];
  const float* relk = (const float*)d_in[5];
  const float* relv = (const float*)d_in[6];
  const float* araw = (const float*)d_in[7];
  float* out = (float*)d_out;

  char* w = (char*)d_ws;
  size_t off = 0;
  auto take = [&](size_t bytes)->char*{ char* p = w + off; off += (bytes + 255) & ~(size_t)255; return p; };

  // regionA (90 MB): phase1 {xS|wqS|qkv32} -> per-half P (77.6 MB) -> {resS|woS}
  char* regionA = take(94371840);
  u16*   xS    = (u16*)  (regionA);
  u16*   wqS   = (u16*)  (regionA + 25165824);
  float* qkv32 = (float*)(regionA + 44040192);
  u16*   Ph    = (u16*)  (regionA);         // [32][1024][1184] u16 per half
  u16*   resS  = (u16*)  (regionA);
  u16*   woS   = (u16*)  (regionA + 25165824);
  u16*   qS    = (u16*)take(25165824);      // [64][1024][192]
  u16*   kxS   = (u16*)take(31457280);      // [64][1280][192]
  u16*   vA    = (u16*)take(9699328);       // [64][64][1184]
  u16*   vB    = (u16*)take(9699328);
  float* res   = (float*)take(16777216);    // [64][1024][64]
  (void)ws_size; (void)in_sizes; (void)n_in; (void)out_size;
  // total ~187 MiB

  // phase 1: QKV projection. qk at split-fp32 (K=3072 planes); v hi*hi (K=1024).
  planeize<<<16384,256,0,stream>>>(x,    xS,  4194304, 0);
  planeize<<<12288,256,0,stream>>>(Wqkv, wqS, 3145728, 1);
  gemm_bt<128,128,0><<<dim3(16,32,1),256,0,stream>>>(xS, wqS, qkv32, bqkv,
      3072, 3072, 3072, 3072, 2048, 0, 0, 0, nullptr, nullptr, nullptr, 0, 0);
  gemm_bt<128,128,0><<<dim3(8,32,1),256,0,stream>>>(xS, wqS + (long long)2048*3072,
      qkv32 + 2048, bqkv + 2048,
      1024, 3072, 3072, 3072, 1024, 0, 0, 0, nullptr, nullptr, nullptr, 0, 0);
  build_qk   <<<16384,256,0,stream>>>(qkv32, qS, kxS);
  build_kxrel<<<4096, 256,0,stream>>>(relk, kxS);
  build_vT   <<<1024, 256,0,stream>>>(qkv32, vA);
  build_vText<<<2560, 256,0,stream>>>(relv, vA);

  // phases 2+3 per 32-head half: fused scores/topk/softmax -> P, then 3x AV
  for (int half = 0; half < 2; ++half) {
    const long long zo = (long long)half * 32;
    score_topk<<<dim3(32,64),256,0,stream>>>(qS + zo*196608, kxS + zo*245760, Ph);
    gemm_bt<64,64,1><<<dim3(1,16,32),256,0,stream>>>(Ph, vA + zo*75776, nullptr, nullptr,
        1184, 1184, 1184, 0, 0, 1212416LL, 75776LL, 0LL,
        vB + zo*75776, res + zo*65536, araw, 0, 0);
    gemm_bt<64,64,1><<<dim3(1,16,32),256,0,stream>>>(Ph, vB + zo*75776, nullptr, nullptr,
        1024, 1184, 1184, 0, 0, 1212416LL, 75776LL, 0LL,
        vA + zo*75776, res + zo*65536, araw, 1, 1);
    gemm_bt<64,64,1><<<dim3(1,16,32),256,0,stream>>>(Ph, vA + zo*75776, nullptr, nullptr,
        1024, 1184, 1184, 0, 0, 1212416LL, 75776LL, 0LL,
        vB + zo*75776, res + zo*65536, araw, 2, 1);
  }

  // output projection (fp32 via split planes), BM=64 for 512-block occupancy
  build_resS<<<16384,256,0,stream>>>(res, resS);
  planeize  <<<4096, 256,0,stream>>>(Wout, woS, 1048576, 1);
  gemm_bt<64,128,0><<<dim3(8,64,1),256,0,stream>>>(resS, woS, out, bout,
      3072, 3072, 3072, 1024, 1024, 0, 0, 0, nullptr, nullptr, nullptr, 0, 0);
}

// Round 6
// 758.977 us; speedup vs baseline: 1.2161x; 1.2161x over previous
//
#include <hip/hip_runtime.h>

typedef unsigned short u16;
typedef unsigned int   u32;
typedef unsigned long long u64;
typedef __bf16 bf16x8 __attribute__((ext_vector_type(8)));
typedef float  floatx4 __attribute__((ext_vector_type(4)));

#define DEV static __device__ __forceinline__

DEV u16 f2bf(float f){ u32 x = __float_as_uint(f); return (u16)((x + 0x7fffu + ((x>>16)&1u)) >> 16); }
DEV float bf2f(u16 h){ return __uint_as_float(((u32)h)<<16); }

DEV void load_lds16(const u16* g, u16* l){
  __builtin_amdgcn_global_load_lds((const __attribute__((address_space(1))) u32*)g,
                                   (__attribute__((address_space(3))) u32*)l, 16, 0, 0);
}

// ---------------------------------------------------------------------------
// Generic NT GEMM: C[m,n] = sum_k A[m,k]*B[n,k]  (A,B bf16 row-major, C fp32)
// BM in {64,128}, BN in {64,128}, BK=32, 256 threads (4 waves as 2x2).
// MODE 0: C fp32 (+optional bias[n]), stores guarded by col<ncmax.
// MODE 1 (BN=64): AV epilogue — res[z][i][d] (+)= alpha*C (alpha=sigmoid),
//   and vout[z][d][i] = bf16(C) (transposed) for the next order.
// ---------------------------------------------------------------------------
template<int BM, int BN, int MODE>
__global__ __launch_bounds__(256) void gemm_bt(
    const u16* __restrict__ A, const u16* __restrict__ Bm, float* __restrict__ C,
    const float* __restrict__ bias, int K, int lda, int ldb, int ldc, int ncmax,
    long long sA, long long sB, long long sC,
    u16* __restrict__ vout, float* __restrict__ resb, const float* __restrict__ araw,
    int order, int accum)
{
  constexpr int BK = 32;
  constexpr int MT = BM/32;               // m-tiles per wave (wave covers BM/2 rows)
  constexpr int NT = (BN/2)/16;           // n-tiles per wave
  __shared__ u16 smem[8704];              // staging (<=8192 u16) / 64x136 transpose
  u16* As = smem;                         // BM*BK u16
  u16* Bs = smem + BM*BK;                 // BN*BK u16

  const int tid = threadIdx.x, wid = tid>>6, lane = tid&63;
  const int z = blockIdx.z;
  const int m0 = blockIdx.y * BM, n0 = blockIdx.x * BN;
  const u16* Ab = A + (long long)z*sA;
  const u16* Bb = Bm + (long long)z*sB;

  const int srow = tid>>2, schunk = (tid&3)*8;
  const u16* ga0 = Ab + (long long)(m0 + srow)*lda + schunk;
  const u16* gb0 = Bb + (long long)(n0 + srow)*ldb + schunk;
  const u16* ga1 = (BM==128) ? Ab + (long long)(m0 + 64 + srow)*lda + schunk : nullptr;
  const u16* gb1 = (BN==128) ? Bb + (long long)(n0 + 64 + srow)*ldb + schunk : nullptr;

  u16* lA0 = As + (wid*16)*BK;
  u16* lA1 = As + (64 + wid*16)*BK;
  u16* lB0 = Bs + (wid*16)*BK;
  u16* lB1 = Bs + (64 + wid*16)*BK;

  const int wm = wid>>1, wn = wid&1;
  const int lr = lane&15, lk = (lane>>4)*8, lq = lane>>4;

  floatx4 acc[MT][NT] = {};

  for (int k = 0; k < K; k += BK) {
    __syncthreads();
    load_lds16(ga0 + k, lA0);
    if constexpr (BM == 128) load_lds16(ga1 + k, lA1);
    load_lds16(gb0 + k, lB0);
    if constexpr (BN == 128) load_lds16(gb1 + k, lB1);
    __syncthreads();
    bf16x8 af[MT];
#pragma unroll
    for (int mt=0; mt<MT; ++mt)
      af[mt] = *(const bf16x8*)(As + (wm*(BM/2) + mt*16 + lr)*BK + lk);
#pragma unroll
    for (int nt=0; nt<NT; ++nt) {
      bf16x8 bfr = *(const bf16x8*)(Bs + (wn*(BN/2) + nt*16 + lr)*BK + lk);
#pragma unroll
      for (int mt=0; mt<MT; ++mt)
        acc[mt][nt] = __builtin_amdgcn_mfma_f32_16x16x32_bf16(af[mt], bfr, acc[mt][nt], 0, 0, 0);
    }
  }

  if constexpr (MODE == 0) {
    float* Cb = C + (long long)z*sC;
#pragma unroll
    for (int nt=0; nt<NT; ++nt) {
      const int col = n0 + wn*(BN/2) + nt*16 + lr;
      if (col < ncmax) {
        const float bv = bias ? bias[col] : 0.f;
#pragma unroll
        for (int mt=0; mt<MT; ++mt) {
#pragma unroll
          for (int r=0; r<4; ++r) {
            const int row = m0 + wm*(BM/2) + mt*16 + lq*4 + r;
            Cb[(long long)row*ldc + col] = acc[mt][nt][r] + bv;
          }
        }
      }
    }
  } else {
    const int h = z & 15;
    const float alpha = 1.f/(1.f + __expf(-araw[order*16 + h]));
    float* rb = resb + (long long)z * 65536;   // res[z][1024][64]
    __syncthreads();                           // staging LDS reuse as transpose buf
#pragma unroll
    for (int nt=0; nt<NT; ++nt) {
      const int d = wn*32 + nt*16 + lr;
#pragma unroll
      for (int mt=0; mt<MT; ++mt) {
#pragma unroll
        for (int r=0; r<4; ++r) {
          const int row = wm*(BM/2) + mt*16 + lq*4 + r;
          const float v = acc[mt][nt][r];
          const long long ri = (long long)(m0+row)*64 + d;
          rb[ri] = accum ? (rb[ri] + alpha*v) : (alpha*v);
          smem[d*136 + row] = f2bf(v);
        }
      }
    }
    __syncthreads();
    const int dd = tid>>2, cc = (tid&3)*(BM/4);
    u16* vp = vout + (long long)z*75776 + (long long)dd*1184 + m0 + cc;  // vout[z][64][1184]
    const u16* sp = smem + dd*136 + cc;
#pragma unroll
    for (int j=0; j<BM/4; j+=8) {
      uint4 uu;
      uu.x = sp[j+0] | ((u32)sp[j+1]<<16);
      uu.y = sp[j+2] | ((u32)sp[j+3]<<16);
      uu.z = sp[j+4] | ((u32)sp[j+5]<<16);
      uu.w = sp[j+6] | ((u32)sp[j+7]<<16);
      *(uint4*)(vp + j) = uu;
    }
  }
}

// ---------------------------------------------------------------------------
// Fused scores + top-k + softmax, v2. qF/kxF are MFMA-fragment-swizzled:
//   layout [z][tile][kc=6][lane=64][elem=8] u16, where tile = row/16,
//   lane = (row&15) + 16*((k&31)>>3), elem = k&7, kc = k>>5.
// So each wave fragment load is ONE contiguous 1 KB global_load_dwordx4.
// One block = (z, 16 Q-rows): wave w computes n-tiles [w*19, w*19+19)
// (cols w*304.., covering 0..1215 >= 1153); scores -> LDS (stride 1156).
// Then wave w owns rows w*4..w*4+3: band-add from own row's rel cols
// (1024..1152), exact early-exit radix select, softmax, write P bf16.
// kc-ascending accumulation matches the old GEMM -> bit-identical scores.
// ---------------------------------------------------------------------------
__global__ __launch_bounds__(256) void score_topk(
    const u16* __restrict__ qF,   // [z][64][6][64][8]
    const u16* __restrict__ kxF,  // [z][80][6][64][8]
    u16* __restrict__ P)          // [z][1024][1184]
{
  constexpr int SROW = 1156;
  __shared__ float sm[16*SROW];   // 73,984 B -> 2 blocks/CU
  const int tid = threadIdx.x, wid = tid>>6, lane = tid&63;
  const int z = blockIdx.x, mt = blockIdx.y, m0 = mt*16;
  const int lr = lane&15, lq = lane>>4;

  const u16* Aq = qF + (((long long)z*64 + mt)*6*64 + lane)*8;
  const u16* Bq = kxF + ((long long)z*80*6*64 + lane)*8;

  bf16x8 af[6];
#pragma unroll
  for (int kc=0;kc<6;++kc) af[kc] = *(const bf16x8*)(Aq + kc*512);

  floatx4 acc[19];
#pragma unroll
  for (int nt=0;nt<19;++nt) acc[nt] = floatx4{0.f,0.f,0.f,0.f};

  const int t0 = wid*19;
#pragma unroll 2
  for (int nt=0;nt<19;++nt){
    const u16* bp = Bq + (long long)(t0+nt)*3072;   // 6*512
    bf16x8 b0 = *(const bf16x8*)(bp);
    bf16x8 b1 = *(const bf16x8*)(bp + 512);
    bf16x8 b2 = *(const bf16x8*)(bp + 1024);
    bf16x8 b3 = *(const bf16x8*)(bp + 1536);
    bf16x8 b4 = *(const bf16x8*)(bp + 2048);
    bf16x8 b5 = *(const bf16x8*)(bp + 2560);
    acc[nt] = __builtin_amdgcn_mfma_f32_16x16x32_bf16(af[0], b0, acc[nt], 0, 0, 0);
    acc[nt] = __builtin_amdgcn_mfma_f32_16x16x32_bf16(af[1], b1, acc[nt], 0, 0, 0);
    acc[nt] = __builtin_amdgcn_mfma_f32_16x16x32_bf16(af[2], b2, acc[nt], 0, 0, 0);
    acc[nt] = __builtin_amdgcn_mfma_f32_16x16x32_bf16(af[3], b3, acc[nt], 0, 0, 0);
    acc[nt] = __builtin_amdgcn_mfma_f32_16x16x32_bf16(af[4], b4, acc[nt], 0, 0, 0);
    acc[nt] = __builtin_amdgcn_mfma_f32_16x16x32_bf16(af[5], b5, acc[nt], 0, 0, 0);
  }
#pragma unroll
  for (int nt=0;nt<19;++nt){
    const int col = (t0+nt)*16 + lr;
    if (col < 1153){
#pragma unroll
      for (int r=0;r<4;++r) sm[(lq*4+r)*SROW + col] = acc[nt][r];
    }
  }
  __syncthreads();

  for (int rr=0; rr<4; ++rr){
    const int row = wid*4 + rr;
    const int i = m0 + row;
    float* R = sm + row*SROW;

    float v[16];
#pragma unroll
    for (int x=0;x<8;++x){
      float2 f = *(const float2*)(R + x*128 + lane*2);
      v[2*x] = f.x; v[2*x+1] = f.y;
    }
#pragma unroll
    for (int x=0;x<16;++x){
      const int j = (x>>1)*128 + lane*2 + (x&1);
      int dl = i - j; dl = dl > 64 ? 64 : (dl < -64 ? -64 : dl);
      v[x] += R[1024 + dl + 64];
    }
    u32 u[16];
#pragma unroll
    for (int x=0;x<16;++x){
      u32 bb = __float_as_uint(v[x]);
      u[x] = bb ^ ((u32)((int)bb >> 31) | 0x80000000u);
    }
    u32 thr = 0;
#pragma unroll 1
    for (int bit=31; bit>=0; --bit){
      const u32 cand = thr | (1u<<bit);
      int c = 0;
#pragma unroll
      for (int x=0;x<16;++x) c += __popcll(__ballot(u[x] >= cand));
      if (c == 256){
        u32 mn = 0xFFFFFFFFu;
#pragma unroll
        for (int x=0;x<16;++x) if (u[x] >= cand && u[x] < mn) mn = u[x];
        for (int o=32;o;o>>=1){ u32 t = __shfl_xor(mn, o); mn = t < mn ? t : mn; }
        thr = mn;
        break;
      }
      if (c > 256) thr = cand;
    }
    float m = -3.0e38f;
#pragma unroll
    for (int x=0;x<16;++x) m = fmaxf(m, v[x]);
    for (int o=32;o;o>>=1) m = fmaxf(m, __shfl_xor(m, o));
    float e[16]; float Z = 0.f;
#pragma unroll
    for (int x=0;x<16;++x){
      e[x] = (u[x] >= thr) ? __expf(v[x]-m) : 0.f;
      Z += e[x];
    }
    for (int o=32;o;o>>=1) Z += __shfl_xor(Z, o);
    const float rz = 1.f / Z;

    u16* Pr = P + ((long long)z*1024 + i)*1184;
    u32* Pr32 = (u32*)Pr;
#pragma unroll
    for (int x=0;x<8;++x){
      const float p0 = e[2*x]*rz, p1 = e[2*x+1]*rz;
      *(float2*)(R + x*128 + lane*2) = float2{p0, p1};
      Pr32[x*64 + lane] = f2bf(p0) | ((u32)f2bf(p1)<<16);
    }
    float s0 = 0.f, s1 = 0.f;
#pragma unroll
    for (int x=0;x<16;++x){
      const int j = (x>>1)*128 + lane*2 + (x&1);
      const float p = e[x]*rz;
      if (j >= i+64) s0 += p;        // dist bucket t=0
      if (j <= i-64) s1 += p;        // dist bucket t=128
    }
    for (int o=32;o;o>>=1){ s0 += __shfl_xor(s0,o); s1 += __shfl_xor(s1,o); }
    {
      const int t = lane + 1;        // 1..64
      const int j = i + 64 - t;
      const float wv = (j>=0 && j<1024) ? R[j] : 0.f;
      Pr[1024 + t] = f2bf(wv);
      if (lane < 63){
        const int t2 = lane + 65;    // 65..127
        const int j2 = i + 64 - t2;
        const float wv2 = (j2>=0 && j2<1024) ? R[j2] : 0.f;
        Pr[1024 + t2] = f2bf(wv2);
      }
      if (lane == 0){ Pr[1024] = f2bf(s0); Pr[1152] = f2bf(s1); }
      if (lane >= 33) Pr[1120 + lane] = 0;  // zero cols 1153..1183
    }
  }
}

// ---------------------------------------------------------------------------
// Elementwise prep kernels
// ---------------------------------------------------------------------------
__global__ __launch_bounds__(256) void planeize(const float* __restrict__ src, u16* __restrict__ dst,
                                                int total, int modeB){
  int idx = blockIdx.x*256 + threadIdx.x;
  if (idx >= total) return;
  int c = idx & 1023, r = idx >> 10;
  float v = src[idx];
  u16 hi = f2bf(v); u16 lo = f2bf(v - bf2f(hi));
  u16* d = dst + (long long)r*3072 + c;
  if (modeB){ d[0]=hi; d[1024]=hi; d[2048]=lo; }
  else      { d[0]=hi; d[1024]=lo; d[2048]=hi; }
}

// qkv -> qF (A planes hi|lo|hi) and kxF rows 0..1023 (B planes hi|hi|lo, k*0.125),
// both in MFMA-fragment-swizzled layout.
__global__ __launch_bounds__(256) void build_qk(const float* __restrict__ qkv,
                                                u16* __restrict__ qF, u16* __restrict__ kxF){
  int idx = blockIdx.x*256 + threadIdx.x;   // ((b*16+h)*1024+n)*64+d
  int d = idx & 63, n = (idx>>6) & 1023, bh = idx >> 16;
  int b = bh >> 4, h = bh & 15;
  long long src = (long long)(b*1024 + n)*3072 + h*64 + d;
  float qv = qkv[src];
  float kv = qkv[src + 1024] * 0.125f;
  u16 qhi=f2bf(qv), qlo=f2bf(qv - bf2f(qhi));
  u16 khi=f2bf(kv), klo=f2bf(kv - bf2f(khi));
  const int lane = (n&15) + (((d&31)>>3)<<4);
  const int elem = d&7, kc0 = d>>5;
  u16* q = qF + ((((long long)bh*64 + (n>>4))*6*64) + lane)*8 + elem;
  q[(kc0+0)*512] = qhi; q[(kc0+2)*512] = qlo; q[(kc0+4)*512] = qhi;
  u16* kx = kxF + ((((long long)bh*80 + (n>>4))*6*64) + lane)*8 + elem;
  kx[(kc0+0)*512] = khi; kx[(kc0+2)*512] = khi; kx[(kc0+4)*512] = klo;
}

// kxF rows 1024..1279: rel_k_emb planes (B-mode), zero pad rows; swizzled.
__global__ __launch_bounds__(256) void build_kxrel(const float* __restrict__ relk, u16* __restrict__ kxF){
  int idx = blockIdx.x*256 + threadIdx.x;   // (bh, t:256, d:64)
  int d = idx & 63, t = (idx>>6) & 255, bh = idx >> 14;
  u16 hi=0, lo=0;
  if (t < 129){ float v = relk[t*64 + d]; hi = f2bf(v); lo = f2bf(v - bf2f(hi)); }
  const int nrow = 1024 + t;
  const int lane = (t&15) + (((d&31)>>3)<<4);
  const int elem = d&7, kc0 = d>>5;
  u16* kx = kxF + ((((long long)bh*80 + (nrow>>4))*6*64) + lane)*8 + elem;
  kx[(kc0+0)*512] = hi; kx[(kc0+2)*512] = hi; kx[(kc0+4)*512] = lo;
}

__global__ __launch_bounds__(256) void build_vT(const float* __restrict__ qkv, u16* __restrict__ vA){
  __shared__ float tb[64][65];
  int bh = blockIdx.x >> 4, ntile = blockIdx.x & 15;
  int b = bh >> 4, h = bh & 15;
  int tid = threadIdx.x;
  int nl = tid >> 2, dc = (tid & 3)*16;
  const float* sp = qkv + (long long)(b*1024 + ntile*64 + nl)*3072 + 2048 + h*64 + dc;
#pragma unroll
  for (int j=0;j<16;j+=4){
    float4 f = *(const float4*)(sp + j);
    tb[dc+j+0][nl]=f.x; tb[dc+j+1][nl]=f.y; tb[dc+j+2][nl]=f.z; tb[dc+j+3][nl]=f.w;
  }
  __syncthreads();
  int d = tid >> 2, nc = (tid & 3)*16;
  u16* dp = vA + ((long long)bh*64 + d)*1184 + ntile*64 + nc;
#pragma unroll
  for (int j=0;j<16;j+=8){
    u16 a0=f2bf(tb[d][nc+j+0]), a1=f2bf(tb[d][nc+j+1]), a2=f2bf(tb[d][nc+j+2]), a3=f2bf(tb[d][nc+j+3]);
    u16 a4=f2bf(tb[d][nc+j+4]), a5=f2bf(tb[d][nc+j+5]), a6=f2bf(tb[d][nc+j+6]), a7=f2bf(tb[d][nc+j+7]);
    uint4 uu; uu.x=a0|((u32)a1<<16); uu.y=a2|((u32)a3<<16); uu.z=a4|((u32)a5<<16); uu.w=a6|((u32)a7<<16);
    *(uint4*)(dp + j) = uu;
  }
}

__global__ __launch_bounds__(256) void build_vText(const float* __restrict__ relv, u16* __restrict__ vA){
  int idx = blockIdx.x*256 + threadIdx.x;   // (bh, d, t:160)
  int t = idx % 160; int rest = idx / 160; int d = rest & 63; int bh = rest >> 6;
  u16 hv = 0;
  if (t < 129) hv = f2bf(relv[t*64 + d]);
  vA[((long long)bh*64 + d)*1184 + 1024 + t] = hv;
}

__global__ __launch_bounds__(256) void build_resS(const float* __restrict__ res, u16* __restrict__ resS){
  int idx = blockIdx.x*256 + threadIdx.x;
  int d = idx & 63, n = (idx>>6) & 1023, bh = idx >> 16;
  int b = bh >> 4, h = bh & 15;
  float v = res[idx];
  u16 hi = f2bf(v), lo = f2bf(v - bf2f(hi));
  u16* p = resS + (long long)(b*1024 + n)*3072 + h*64 + d;
  p[0]=hi; p[1024]=lo; p[2048]=hi;
}

// ---------------------------------------------------------------------------
extern "C" void kernel_launch(void* const* d_in, const int* in_sizes, int n_in,
                              void* d_out, int out_size, void* d_ws, size_t ws_size,
                              hipStream_t stream) {
  const float* x    = (const float*)d_in[0];
  const float* Wqkv = (const float*)d_in[1];
  const float* bqkv = (const float*)d_in[2];
  const float* Wout = (const float*)d_in[3];
  const float* bout = (const float*)d_in[4];
  const float* relk = (const float*)d_in[5];
  const float* relv = (const float*)d_in[6];
  const float* araw = (const float*)d_in[7];
  float* out = (float*)d_out;

  char* w = (char*)d_ws;
  size_t off = 0;
  auto take = [&](size_t bytes)->char*{ char* p = w + off; off += (bytes + 255) & ~(size_t)255; return p; };

  // regionA (90 MB): phase1 {xS|wqS|qkv32} -> per-half P (77.6 MB) -> {resS|woS}
  char* regionA = take(94371840);
  u16*   xS    = (u16*)  (regionA);
  u16*   wqS   = (u16*)  (regionA + 25165824);
  float* qkv32 = (float*)(regionA + 44040192);
  u16*   Ph    = (u16*)  (regionA);         // [32][1024][1184] u16 per half
  u16*   resS  = (u16*)  (regionA);
  u16*   woS   = (u16*)  (regionA + 25165824);
  u16*   qF    = (u16*)take(25165824);      // [64][64][6][64][8]
  u16*   kxF   = (u16*)take(31457280);      // [64][80][6][64][8]
  u16*   vA    = (u16*)take(9699328);       // [64][64][1184]
  u16*   vB    = (u16*)take(9699328);
  float* res   = (float*)take(16777216);    // [64][1024][64]
  (void)ws_size; (void)in_sizes; (void)n_in; (void)out_size;
  // total ~187 MiB

  // phase 1: QKV projection. qk at split-fp32 (K=3072 planes); v hi*hi (K=1024).
  planeize<<<16384,256,0,stream>>>(x,    xS,  4194304, 0);
  planeize<<<12288,256,0,stream>>>(Wqkv, wqS, 3145728, 1);
  gemm_bt<128,128,0><<<dim3(16,32,1),256,0,stream>>>(xS, wqS, qkv32, bqkv,
      3072, 3072, 3072, 3072, 2048, 0, 0, 0, nullptr, nullptr, nullptr, 0, 0);
  gemm_bt<128,128,0><<<dim3(8,32,1),256,0,stream>>>(xS, wqS + (long long)2048*3072,
      qkv32 + 2048, bqkv + 2048,
      1024, 3072, 3072, 3072, 1024, 0, 0, 0, nullptr, nullptr, nullptr, 0, 0);
  build_qk   <<<16384,256,0,stream>>>(qkv32, qF, kxF);
  build_kxrel<<<4096, 256,0,stream>>>(relk, kxF);
  build_vT   <<<1024, 256,0,stream>>>(qkv32, vA);
  build_vText<<<2560, 256,0,stream>>>(relv, vA);

  // phases 2+3 per 32-head half: fused scores/topk/softmax -> P, then 3x AV
  for (int half = 0; half < 2; ++half) {
    const long long zo = (long long)half * 32;
    score_topk<<<dim3(32,64),256,0,stream>>>(qF + zo*196608, kxF + zo*245760, Ph);
    gemm_bt<64,64,1><<<dim3(1,16,32),256,0,stream>>>(Ph, vA + zo*75776, nullptr, nullptr,
        1184, 1184, 1184, 0, 0, 1212416LL, 75776LL, 0LL,
        vB + zo*75776, res + zo*65536, araw, 0, 0);
    gemm_bt<64,64,1><<<dim3(1,16,32),256,0,stream>>>(Ph, vB + zo*75776, nullptr, nullptr,
        1024, 1184, 1184, 0, 0, 1212416LL, 75776LL, 0LL,
        vA + zo*75776, res + zo*65536, araw, 1, 1);
    gemm_bt<64,64,1><<<dim3(1,16,32),256,0,stream>>>(Ph, vA + zo*75776, nullptr, nullptr,
        1024, 1184, 1184, 0, 0, 1212416LL, 75776LL, 0LL,
        vB + zo*75776, res + zo*65536, araw, 2, 1);
  }

  // output projection (fp32 via split planes), BM=64 for 512-block occupancy
  build_resS<<<16384,256,0,stream>>>(res, resS);
  planeize  <<<4096, 256,0,stream>>>(Wout, woS, 1048576, 1);
  gemm_bt<64,128,0><<<dim3(8,64,1),256,0,stream>>>(resS, woS, out, bout,
      3072, 3072, 3072, 1024, 1024, 0, 0, 0, nullptr, nullptr, nullptr, 0, 0);
}

// Round 7
// 658.720 us; speedup vs baseline: 1.4012x; 1.1522x over previous
//
#include <hip/hip_runtime.h>

typedef unsigned short u16;
typedef unsigned int   u32;
typedef unsigned long long u64;
typedef __bf16 bf16x8 __attribute__((ext_vector_type(8)));
typedef float  floatx4 __attribute__((ext_vector_type(4)));

#define DEV static __device__ __forceinline__

DEV u16 f2bf(float f){ u32 x = __float_as_uint(f); return (u16)((x + 0x7fffu + ((x>>16)&1u)) >> 16); }
DEV float bf2f(u16 h){ return __uint_as_float(((u32)h)<<16); }

DEV void load_lds16(const u16* g, u16* l){
  __builtin_amdgcn_global_load_lds((const __attribute__((address_space(1))) u32*)g,
                                   (__attribute__((address_space(3))) u32*)l, 16, 0, 0);
}

// ---------------------------------------------------------------------------
// Generic NT GEMM: C[m,n] = sum_k A[m,k]*B[n,k]  (A,B bf16 row-major, C fp32)
// BM in {64,128}, BN in {64,128}, BK=32, 256 threads (4 waves as 2x2).
// MODE 0: C fp32 (+optional bias[n]), stores guarded by col<ncmax.
// MODE 1 (BN=64): AV epilogue — res[z][i][d] (+)= alpha*C (alpha=sigmoid),
//   and vout[z][d][i] = bf16(C) (transposed) for the next order.
// ---------------------------------------------------------------------------
template<int BM, int BN, int MODE>
__global__ __launch_bounds__(256) void gemm_bt(
    const u16* __restrict__ A, const u16* __restrict__ Bm, float* __restrict__ C,
    const float* __restrict__ bias, int K, int lda, int ldb, int ldc, int ncmax,
    long long sA, long long sB, long long sC,
    u16* __restrict__ vout, float* __restrict__ resb, const float* __restrict__ araw,
    int order, int accum)
{
  constexpr int BK = 32;
  constexpr int MT = BM/32;               // m-tiles per wave (wave covers BM/2 rows)
  constexpr int NT = (BN/2)/16;           // n-tiles per wave
  __shared__ u16 smem[8704];              // staging (<=8192 u16) / 64x136 transpose
  u16* As = smem;                         // BM*BK u16
  u16* Bs = smem + BM*BK;                 // BN*BK u16

  const int tid = threadIdx.x, wid = tid>>6, lane = tid&63;
  const int z = blockIdx.z;
  const int m0 = blockIdx.y * BM, n0 = blockIdx.x * BN;
  const u16* Ab = A + (long long)z*sA;
  const u16* Bb = Bm + (long long)z*sB;

  const int srow = tid>>2, schunk = (tid&3)*8;
  const u16* ga0 = Ab + (long long)(m0 + srow)*lda + schunk;
  const u16* gb0 = Bb + (long long)(n0 + srow)*ldb + schunk;
  const u16* ga1 = (BM==128) ? Ab + (long long)(m0 + 64 + srow)*lda + schunk : nullptr;
  const u16* gb1 = (BN==128) ? Bb + (long long)(n0 + 64 + srow)*ldb + schunk : nullptr;

  u16* lA0 = As + (wid*16)*BK;
  u16* lA1 = As + (64 + wid*16)*BK;
  u16* lB0 = Bs + (wid*16)*BK;
  u16* lB1 = Bs + (64 + wid*16)*BK;

  const int wm = wid>>1, wn = wid&1;
  const int lr = lane&15, lk = (lane>>4)*8, lq = lane>>4;

  floatx4 acc[MT][NT] = {};

  for (int k = 0; k < K; k += BK) {
    __syncthreads();
    load_lds16(ga0 + k, lA0);
    if constexpr (BM == 128) load_lds16(ga1 + k, lA1);
    load_lds16(gb0 + k, lB0);
    if constexpr (BN == 128) load_lds16(gb1 + k, lB1);
    __syncthreads();
    bf16x8 af[MT];
#pragma unroll
    for (int mt=0; mt<MT; ++mt)
      af[mt] = *(const bf16x8*)(As + (wm*(BM/2) + mt*16 + lr)*BK + lk);
#pragma unroll
    for (int nt=0; nt<NT; ++nt) {
      bf16x8 bfr = *(const bf16x8*)(Bs + (wn*(BN/2) + nt*16 + lr)*BK + lk);
#pragma unroll
      for (int mt=0; mt<MT; ++mt)
        acc[mt][nt] = __builtin_amdgcn_mfma_f32_16x16x32_bf16(af[mt], bfr, acc[mt][nt], 0, 0, 0);
    }
  }

  if constexpr (MODE == 0) {
    float* Cb = C + (long long)z*sC;
#pragma unroll
    for (int nt=0; nt<NT; ++nt) {
      const int col = n0 + wn*(BN/2) + nt*16 + lr;
      if (col < ncmax) {
        const float bv = bias ? bias[col] : 0.f;
#pragma unroll
        for (int mt=0; mt<MT; ++mt) {
#pragma unroll
          for (int r=0; r<4; ++r) {
            const int row = m0 + wm*(BM/2) + mt*16 + lq*4 + r;
            Cb[(long long)row*ldc + col] = acc[mt][nt][r] + bv;
          }
        }
      }
    }
  } else {
    const int h = z & 15;
    const float alpha = 1.f/(1.f + __expf(-araw[order*16 + h]));
    float* rb = resb + (long long)z * 65536;   // res[z][1024][64]
    __syncthreads();                           // staging LDS reuse as transpose buf
#pragma unroll
    for (int nt=0; nt<NT; ++nt) {
      const int d = wn*32 + nt*16 + lr;
#pragma unroll
      for (int mt=0; mt<MT; ++mt) {
#pragma unroll
        for (int r=0; r<4; ++r) {
          const int row = wm*(BM/2) + mt*16 + lq*4 + r;
          const float v = acc[mt][nt][r];
          const long long ri = (long long)(m0+row)*64 + d;
          rb[ri] = accum ? (rb[ri] + alpha*v) : (alpha*v);
          smem[d*136 + row] = f2bf(v);
        }
      }
    }
    __syncthreads();
    const int dd = tid>>2, cc = (tid&3)*(BM/4);
    u16* vp = vout + (long long)z*75776 + (long long)dd*1184 + m0 + cc;  // vout[z][64][1184]
    const u16* sp = smem + dd*136 + cc;
#pragma unroll
    for (int j=0; j<BM/4; j+=8) {
      uint4 uu;
      uu.x = sp[j+0] | ((u32)sp[j+1]<<16);
      uu.y = sp[j+2] | ((u32)sp[j+3]<<16);
      uu.z = sp[j+4] | ((u32)sp[j+5]<<16);
      uu.w = sp[j+6] | ((u32)sp[j+7]<<16);
      *(uint4*)(vp + j) = uu;
    }
  }
}

// ---------------------------------------------------------------------------
// Fused scores + top-k + softmax, v3. qF/kxF are MFMA-fragment-swizzled
// ([z][tile][kc=6][lane=64][elem=8] u16) so each fragment load is one
// contiguous 1 KB global_load_dwordx4.
// Grid is LINEAR (2048 blocks); decode z = (L&7) + 8*(L>>9), mt = (L>>3)&63:
// consecutive blocks on one XCD share one z -> that z's kxF (480 KB) stays
// resident in the XCD's 4 MB L2 (R6 interleaved z across XCDs and thrashed
// L2 -> L3-bandwidth-bound at 157 us).
// 512 threads (8 waves) -> with 74 KB LDS: 2 blocks/CU = 4 waves/SIMD (2x R6
// TLP). Wave w computes n-tiles [w*10, w*10+10) in two 5-tile chunks (acc[5]
// in AGPRs, predicated base+t<73), stores scores to LDS (stride 1156), then
// owns rows w*2..w*2+1 for band-add + exact early-exit radix top-k + softmax.
// kc-ascending per-tile accumulation -> scores bit-identical to R4-R6.
// ---------------------------------------------------------------------------
__global__ __launch_bounds__(512, 4) void score_topk(
    const u16* __restrict__ qF,   // [z][64][6][64][8]
    const u16* __restrict__ kxF,  // [z][80][6][64][8]
    u16* __restrict__ P)          // [z][1024][1184]
{
  constexpr int SROW = 1156;
  __shared__ float sm[16*SROW];   // 73,984 B -> 2 blocks/CU
  const int tid = threadIdx.x, wid = tid>>6, lane = tid&63;
  const int L = blockIdx.x;
  const int z  = (L & 7) + ((L >> 9) << 3);
  const int mt = (L >> 3) & 63;
  const int m0 = mt*16;
  const int lr = lane&15, lq = lane>>4;

  const u16* Aq = qF + (((long long)z*64 + mt)*6*64 + lane)*8;
  const u16* Bq = kxF + ((long long)z*80*6*64 + lane)*8;

  bf16x8 af[6];
#pragma unroll
  for (int kc=0;kc<6;++kc) af[kc] = *(const bf16x8*)(Aq + kc*512);

  const int nt0 = wid*10;
#pragma unroll
  for (int h=0; h<2; ++h){
    const int base = nt0 + h*5;
    floatx4 acc[5];
#pragma unroll
    for (int t=0;t<5;++t) acc[t] = floatx4{0.f,0.f,0.f,0.f};
#pragma unroll
    for (int t=0;t<5;++t){
      if (base + t < 73){
        const u16* bp = Bq + (long long)(base+t)*3072;   // 6*512
        bf16x8 b0 = *(const bf16x8*)(bp);
        bf16x8 b1 = *(const bf16x8*)(bp + 512);
        bf16x8 b2 = *(const bf16x8*)(bp + 1024);
        bf16x8 b3 = *(const bf16x8*)(bp + 1536);
        bf16x8 b4 = *(const bf16x8*)(bp + 2048);
        bf16x8 b5 = *(const bf16x8*)(bp + 2560);
        acc[t] = __builtin_amdgcn_mfma_f32_16x16x32_bf16(af[0], b0, acc[t], 0, 0, 0);
        acc[t] = __builtin_amdgcn_mfma_f32_16x16x32_bf16(af[1], b1, acc[t], 0, 0, 0);
        acc[t] = __builtin_amdgcn_mfma_f32_16x16x32_bf16(af[2], b2, acc[t], 0, 0, 0);
        acc[t] = __builtin_amdgcn_mfma_f32_16x16x32_bf16(af[3], b3, acc[t], 0, 0, 0);
        acc[t] = __builtin_amdgcn_mfma_f32_16x16x32_bf16(af[4], b4, acc[t], 0, 0, 0);
        acc[t] = __builtin_amdgcn_mfma_f32_16x16x32_bf16(af[5], b5, acc[t], 0, 0, 0);
      }
    }
#pragma unroll
    for (int t=0;t<5;++t){
      if (base + t < 73){
        const int col = (base+t)*16 + lr;
        if (col < 1153){
#pragma unroll
          for (int r=0;r<4;++r) sm[(lq*4+r)*SROW + col] = acc[t][r];
        }
      }
    }
  }
  __syncthreads();

  for (int rr=0; rr<2; ++rr){
    const int row = wid*2 + rr;
    const int i = m0 + row;
    float* R = sm + row*SROW;

    float v[16];
#pragma unroll
    for (int x=0;x<8;++x){
      float2 f = *(const float2*)(R + x*128 + lane*2);
      v[2*x] = f.x; v[2*x+1] = f.y;
    }
#pragma unroll
    for (int x=0;x<16;++x){
      const int j = (x>>1)*128 + lane*2 + (x&1);
      int dl = i - j; dl = dl > 64 ? 64 : (dl < -64 ? -64 : dl);
      v[x] += R[1024 + dl + 64];
    }
    u32 u[16];
#pragma unroll
    for (int x=0;x<16;++x){
      u32 bb = __float_as_uint(v[x]);
      u[x] = bb ^ ((u32)((int)bb >> 31) | 0x80000000u);
    }
    u32 thr = 0;
#pragma unroll 1
    for (int bit=31; bit>=0; --bit){
      const u32 cand = thr | (1u<<bit);
      int c = 0;
#pragma unroll
      for (int x=0;x<16;++x) c += __popcll(__ballot(u[x] >= cand));
      if (c == 256){
        u32 mn = 0xFFFFFFFFu;
#pragma unroll
        for (int x=0;x<16;++x) if (u[x] >= cand && u[x] < mn) mn = u[x];
        for (int o=32;o;o>>=1){ u32 t = __shfl_xor(mn, o); mn = t < mn ? t : mn; }
        thr = mn;
        break;
      }
      if (c > 256) thr = cand;
    }
    float m = -3.0e38f;
#pragma unroll
    for (int x=0;x<16;++x) m = fmaxf(m, v[x]);
    for (int o=32;o;o>>=1) m = fmaxf(m, __shfl_xor(m, o));
    float e[16]; float Z = 0.f;
#pragma unroll
    for (int x=0;x<16;++x){
      e[x] = (u[x] >= thr) ? __expf(v[x]-m) : 0.f;
      Z += e[x];
    }
    for (int o=32;o;o>>=1) Z += __shfl_xor(Z, o);
    const float rz = 1.f / Z;

    u16* Pr = P + ((long long)z*1024 + i)*1184;
    u32* Pr32 = (u32*)Pr;
#pragma unroll
    for (int x=0;x<8;++x){
      const float p0 = e[2*x]*rz, p1 = e[2*x+1]*rz;
      *(float2*)(R + x*128 + lane*2) = float2{p0, p1};
      Pr32[x*64 + lane] = f2bf(p0) | ((u32)f2bf(p1)<<16);
    }
    float s0 = 0.f, s1 = 0.f;
#pragma unroll
    for (int x=0;x<16;++x){
      const int j = (x>>1)*128 + lane*2 + (x&1);
      const float p = e[x]*rz;
      if (j >= i+64) s0 += p;        // dist bucket t=0
      if (j <= i-64) s1 += p;        // dist bucket t=128
    }
    for (int o=32;o;o>>=1){ s0 += __shfl_xor(s0,o); s1 += __shfl_xor(s1,o); }
    {
      const int t = lane + 1;        // 1..64
      const int j = i + 64 - t;
      const float wv = (j>=0 && j<1024) ? R[j] : 0.f;
      Pr[1024 + t] = f2bf(wv);
      if (lane < 63){
        const int t2 = lane + 65;    // 65..127
        const int j2 = i + 64 - t2;
        const float wv2 = (j2>=0 && j2<1024) ? R[j2] : 0.f;
        Pr[1024 + t2] = f2bf(wv2);
      }
      if (lane == 0){ Pr[1024] = f2bf(s0); Pr[1152] = f2bf(s1); }
      if (lane >= 33) Pr[1120 + lane] = 0;  // zero cols 1153..1183
    }
  }
}

// ---------------------------------------------------------------------------
// Elementwise prep kernels
// ---------------------------------------------------------------------------
__global__ __launch_bounds__(256) void planeize(const float* __restrict__ src, u16* __restrict__ dst,
                                                int total, int modeB){
  int idx = blockIdx.x*256 + threadIdx.x;
  if (idx >= total) return;
  int c = idx & 1023, r = idx >> 10;
  float v = src[idx];
  u16 hi = f2bf(v); u16 lo = f2bf(v - bf2f(hi));
  u16* d = dst + (long long)r*3072 + c;
  if (modeB){ d[0]=hi; d[1024]=hi; d[2048]=lo; }
  else      { d[0]=hi; d[1024]=lo; d[2048]=hi; }
}

// qkv -> qF (A planes hi|lo|hi) and kxF rows 0..1023 (B planes hi|hi|lo, k*0.125),
// both in MFMA-fragment-swizzled layout.
__global__ __launch_bounds__(256) void build_qk(const float* __restrict__ qkv,
                                                u16* __restrict__ qF, u16* __restrict__ kxF){
  int idx = blockIdx.x*256 + threadIdx.x;   // ((b*16+h)*1024+n)*64+d
  int d = idx & 63, n = (idx>>6) & 1023, bh = idx >> 16;
  int b = bh >> 4, h = bh & 15;
  long long src = (long long)(b*1024 + n)*3072 + h*64 + d;
  float qv = qkv[src];
  float kv = qkv[src + 1024] * 0.125f;
  u16 qhi=f2bf(qv), qlo=f2bf(qv - bf2f(qhi));
  u16 khi=f2bf(kv), klo=f2bf(kv - bf2f(khi));
  const int lane = (n&15) + (((d&31)>>3)<<4);
  const int elem = d&7, kc0 = d>>5;
  u16* q = qF + ((((long long)bh*64 + (n>>4))*6*64) + lane)*8 + elem;
  q[(kc0+0)*512] = qhi; q[(kc0+2)*512] = qlo; q[(kc0+4)*512] = qhi;
  u16* kx = kxF + ((((long long)bh*80 + (n>>4))*6*64) + lane)*8 + elem;
  kx[(kc0+0)*512] = khi; kx[(kc0+2)*512] = khi; kx[(kc0+4)*512] = klo;
}

// kxF rows 1024..1279: rel_k_emb planes (B-mode), zero pad rows; swizzled.
__global__ __launch_bounds__(256) void build_kxrel(const float* __restrict__ relk, u16* __restrict__ kxF){
  int idx = blockIdx.x*256 + threadIdx.x;   // (bh, t:256, d:64)
  int d = idx & 63, t = (idx>>6) & 255, bh = idx >> 14;
  u16 hi=0, lo=0;
  if (t < 129){ float v = relk[t*64 + d]; hi = f2bf(v); lo = f2bf(v - bf2f(hi)); }
  const int nrow = 1024 + t;
  const int lane = (t&15) + (((d&31)>>3)<<4);
  const int elem = d&7, kc0 = d>>5;
  u16* kx = kxF + ((((long long)bh*80 + (nrow>>4))*6*64) + lane)*8 + elem;
  kx[(kc0+0)*512] = hi; kx[(kc0+2)*512] = hi; kx[(kc0+4)*512] = lo;
}

__global__ __launch_bounds__(256) void build_vT(const float* __restrict__ qkv, u16* __restrict__ vA){
  __shared__ float tb[64][65];
  int bh = blockIdx.x >> 4, ntile = blockIdx.x & 15;
  int b = bh >> 4, h = bh & 15;
  int tid = threadIdx.x;
  int nl = tid >> 2, dc = (tid & 3)*16;
  const float* sp = qkv + (long long)(b*1024 + ntile*64 + nl)*3072 + 2048 + h*64 + dc;
#pragma unroll
  for (int j=0;j<16;j+=4){
    float4 f = *(const float4*)(sp + j);
    tb[dc+j+0][nl]=f.x; tb[dc+j+1][nl]=f.y; tb[dc+j+2][nl]=f.z; tb[dc+j+3][nl]=f.w;
  }
  __syncthreads();
  int d = tid >> 2, nc = (tid & 3)*16;
  u16* dp = vA + ((long long)bh*64 + d)*1184 + ntile*64 + nc;
#pragma unroll
  for (int j=0;j<16;j+=8){
    u16 a0=f2bf(tb[d][nc+j+0]), a1=f2bf(tb[d][nc+j+1]), a2=f2bf(tb[d][nc+j+2]), a3=f2bf(tb[d][nc+j+3]);
    u16 a4=f2bf(tb[d][nc+j+4]), a5=f2bf(tb[d][nc+j+5]), a6=f2bf(tb[d][nc+j+6]), a7=f2bf(tb[d][nc+j+7]);
    uint4 uu; uu.x=a0|((u32)a1<<16); uu.y=a2|((u32)a3<<16); uu.z=a4|((u32)a5<<16); uu.w=a6|((u32)a7<<16);
    *(uint4*)(dp + j) = uu;
  }
}

__global__ __launch_bounds__(256) void build_vText(const float* __restrict__ relv, u16* __restrict__ vA){
  int idx = blockIdx.x*256 + threadIdx.x;   // (bh, d, t:160)
  int t = idx % 160; int rest = idx / 160; int d = rest & 63; int bh = rest >> 6;
  u16 hv = 0;
  if (t < 129) hv = f2bf(relv[t*64 + d]);
  vA[((long long)bh*64 + d)*1184 + 1024 + t] = hv;
}

__global__ __launch_bounds__(256) void build_resS(const float* __restrict__ res, u16* __restrict__ resS){
  int idx = blockIdx.x*256 + threadIdx.x;
  int d = idx & 63, n = (idx>>6) & 1023, bh = idx >> 16;
  int b = bh >> 4, h = bh & 15;
  float v = res[idx];
  u16 hi = f2bf(v), lo = f2bf(v - bf2f(hi));
  u16* p = resS + (long long)(b*1024 + n)*3072 + h*64 + d;
  p[0]=hi; p[1024]=lo; p[2048]=hi;
}

// ---------------------------------------------------------------------------
extern "C" void kernel_launch(void* const* d_in, const int* in_sizes, int n_in,
                              void* d_out, int out_size, void* d_ws, size_t ws_size,
                              hipStream_t stream) {
  const float* x    = (const float*)d_in[0];
  const float* Wqkv = (const float*)d_in[1];
  const float* bqkv = (const float*)d_in[2];
  const float* Wout = (const float*)d_in[3];
  const float* bout = (const float*)d_in[4];
  const float* relk = (const float*)d_in[5];
  const float* relv = (const float*)d_in[6];
  const float* araw = (const float*)d_in[7];
  float* out = (float*)d_out;

  char* w = (char*)d_ws;
  size_t off = 0;
  auto take = [&](size_t bytes)->char*{ char* p = w + off; off += (bytes + 255) & ~(size_t)255; return p; };

  // regionA (90 MB): phase1 {xS|wqS|qkv32} -> per-half P (77.6 MB) -> {resS|woS}
  char* regionA = take(94371840);
  u16*   xS    = (u16*)  (regionA);
  u16*   wqS   = (u16*)  (regionA + 25165824);
  float* qkv32 = (float*)(regionA + 44040192);
  u16*   Ph    = (u16*)  (regionA);         // [32][1024][1184] u16 per half
  u16*   resS  = (u16*)  (regionA);
  u16*   woS   = (u16*)  (regionA + 25165824);
  u16*   qF    = (u16*)take(25165824);      // [64][64][6][64][8]
  u16*   kxF   = (u16*)take(31457280);      // [64][80][6][64][8]
  u16*   vA    = (u16*)take(9699328);       // [64][64][1184]
  u16*   vB    = (u16*)take(9699328);
  float* res   = (float*)take(16777216);    // [64][1024][64]
  (void)ws_size; (void)in_sizes; (void)n_in; (void)out_size;
  // total ~187 MiB

  // phase 1: QKV projection. qk at split-fp32 (K=3072 planes); v hi*hi (K=1024).
  planeize<<<16384,256,0,stream>>>(x,    xS,  4194304, 0);
  planeize<<<12288,256,0,stream>>>(Wqkv, wqS, 3145728, 1);
  gemm_bt<128,128,0><<<dim3(16,32,1),256,0,stream>>>(xS, wqS, qkv32, bqkv,
      3072, 3072, 3072, 3072, 2048, 0, 0, 0, nullptr, nullptr, nullptr, 0, 0);
  gemm_bt<128,128,0><<<dim3(8,32,1),256,0,stream>>>(xS, wqS + (long long)2048*3072,
      qkv32 + 2048, bqkv + 2048,
      1024, 3072, 3072, 3072, 1024, 0, 0, 0, nullptr, nullptr, nullptr, 0, 0);
  build_qk   <<<16384,256,0,stream>>>(qkv32, qF, kxF);
  build_kxrel<<<4096, 256,0,stream>>>(relk, kxF);
  build_vT   <<<1024, 256,0,stream>>>(qkv32, vA);
  build_vText<<<2560, 256,0,stream>>>(relv, vA);

  // phases 2+3 per 32-head half: fused scores/topk/softmax -> P, then 3x AV
  for (int half = 0; half < 2; ++half) {
    const long long zo = (long long)half * 32;
    score_topk<<<2048,512,0,stream>>>(qF + zo*196608, kxF + zo*245760, Ph);
    gemm_bt<64,64,1><<<dim3(1,16,32),256,0,stream>>>(Ph, vA + zo*75776, nullptr, nullptr,
        1184, 1184, 1184, 0, 0, 1212416LL, 75776LL, 0LL,
        vB + zo*75776, res + zo*65536, araw, 0, 0);
    gemm_bt<64,64,1><<<dim3(1,16,32),256,0,stream>>>(Ph, vB + zo*75776, nullptr, nullptr,
        1024, 1184, 1184, 0, 0, 1212416LL, 75776LL, 0LL,
        vA + zo*75776, res + zo*65536, araw, 1, 1);
    gemm_bt<64,64,1><<<dim3(1,16,32),256,0,stream>>>(Ph, vA + zo*75776, nullptr, nullptr,
        1024, 1184, 1184, 0, 0, 1212416LL, 75776LL, 0LL,
        vB + zo*75776, res + zo*65536, araw, 2, 1);
  }

  // output projection (fp32 via split planes), BM=64 for 512-block occupancy
  build_resS<<<16384,256,0,stream>>>(res, resS);
  planeize  <<<4096, 256,0,stream>>>(Wout, woS, 1048576, 1);
  gemm_bt<64,128,0><<<dim3(8,64,1),256,0,stream>>>(resS, woS, out, bout,
      3072, 3072, 3072, 1024, 1024, 0, 0, 0, nullptr, nullptr, nullptr, 0, 0);
}